// Round 1
// 2181.852 us; speedup vs baseline: 2.5120x; 2.5120x over previous
//
#include <hip/hip_runtime.h>
#include <math.h>

// ---------- types ----------
typedef short v8s __attribute__((ext_vector_type(8)));   // 8 x bf16 (bits)
typedef float v4f __attribute__((ext_vector_type(4)));

// Problem constants
#define B_   32
#define S_   128
#define V_   32000
#define E_   512
#define G_   1024
#define HI_  512
#define NN_  16
#define NH_  8
#define DH_  64
#define TSTEPS 127          // scan steps
#define LOGN  4064000L      // 127*32000, per-batch logit stride
#define SCAN_BLOCKS 128

__device__ __forceinline__ short to_bf16(float x) {
  union { float f; unsigned u; } a; a.f = x;
  unsigned r = (a.u + 0x7FFFu + ((a.u >> 16) & 1u)) >> 16;  // RNE
  return (short)r;
}
__device__ __forceinline__ float sigf(float x) { return 1.f / (1.f + expf(-x)); }

__device__ __forceinline__ void load_lds16(const void* g, void* l) {
  // async global->LDS, 16B per lane, dest = wave-uniform base + lane*16
  __builtin_amdgcn_global_load_lds((const __attribute__((address_space(1))) void*)g,
                                   (__attribute__((address_space(3))) void*)l, 16, 0, 0);
}

// ---------- prep: bf16 weight conversion + bias sum + output passthrough + flags=0 ----------
__global__ void prep_kernel(const float* __restrict__ Wih, const float* __restrict__ Whh,
                            const float* __restrict__ Wout, const float* __restrict__ bih,
                            const float* __restrict__ bhh, const int* __restrict__ sent,
                            const int* __restrict__ slen,
                            short* __restrict__ Wih_b, short* __restrict__ Whh_b,
                            short* __restrict__ Wout_b, float* __restrict__ bsum,
                            float* __restrict__ outTail, unsigned* __restrict__ flags) {
  const long nWo = 32768000L, nWh = 4194304L, nWi = 2097152L;
  const long NT = nWo + nWh + nWi + 4096 + 4096 + 32 + 128;
  long stride = (long)gridDim.x * blockDim.x;
  for (long i = (long)blockIdx.x * blockDim.x + threadIdx.x; i < NT; i += stride) {
    if (i < nWo) { Wout_b[i] = to_bf16(Wout[i]); continue; }
    long j = i - nWo;
    if (j < nWh) { Whh_b[j] = to_bf16(Whh[j]); continue; }
    j -= nWh;
    if (j < nWi) { Wih_b[j] = to_bf16(Wih[j]); continue; }
    j -= nWi;
    if (j < 4096) { bsum[j] = bih[j] + bhh[j]; continue; }
    j -= 4096;
    if (j < 4096) { outTail[j] = (float)sent[j]; continue; }  // target_sent passthrough
    j -= 4096;
    if (j < 32) { outTail[4096 + j] = (float)slen[j]; continue; }  // lens passthrough
    j -= 32;
    flags[j] = 0u;                                            // barrier flags (128)
  }
}

// ---------- generic small GEMM: out[m][n] = X[m]·W[n] + bias[n], optional tanh ----------
__global__ void dotk(const float* __restrict__ X, const float* __restrict__ W,
                     const float* __restrict__ bias, float* __restrict__ out,
                     int M, int N, int K, int act) {
  int o = blockIdx.x * 256 + threadIdx.x;
  if (o >= M * N) return;
  int m = o / N, n = o % N;
  const float4* x4 = (const float4*)(X + (long)m * K);
  const float4* w4 = (const float4*)(W + (long)n * K);
  float s = 0.f;
  int k4 = K >> 2;
  for (int k = 0; k < k4; ++k) {
    float4 a = x4[k], b = w4[k];
    s += a.x * b.x + a.y * b.y + a.z * b.z + a.w * b.w;
  }
  s += bias[n];
  if (act) s = tanhf(s);
  out[o] = s;
}

// ---------- attention core: per (b,head) scores/softmax/weighted-V ----------
__global__ void attnk(const float* __restrict__ q, const float* __restrict__ k,
                      const float* __restrict__ v, const int* __restrict__ nnum,
                      float* __restrict__ ctx) {
  __shared__ float sc[NN_], at[NN_];
  int blk = blockIdx.x;          // 0..255
  int b = blk >> 3, h = blk & 7;
  int t = threadIdx.x;           // 0..63
  if (t < NN_) {
    const float* qp = q + b * HI_ + h * DH_;
    const float* kp = k + (long)(b * NN_ + t) * HI_ + h * DH_;
    float s = 0.f;
    for (int d = 0; d < DH_; ++d) s += qp[d] * kp[d];
    s *= 0.125f;                         // 1/sqrt(64)
    if (t >= nnum[b]) s = -1e9f;         // mask: neighbor_num <= n
    sc[t] = s;
  }
  __syncthreads();
  if (t == 0) {
    float mx = sc[0];
    for (int n = 1; n < NN_; ++n) mx = fmaxf(mx, sc[n]);
    float sum = 0.f;
    for (int n = 0; n < NN_; ++n) { float e = expf(sc[n] - mx); at[n] = e; sum += e; }
    float inv = 1.f / sum;
    for (int n = 0; n < NN_; ++n) at[n] *= inv;
  }
  __syncthreads();
  float acc = 0.f;
  for (int n = 0; n < NN_; ++n)
    acc += at[n] * v[(long)(b * NN_ + n) * HI_ + h * DH_ + t];
  ctx[b * HI_ + h * DH_ + t] = acc;
}

// ---------- concat [entity | attn_out | img] ----------
__global__ void concatk(const float* __restrict__ ent, const float* __restrict__ ao,
                        const float* __restrict__ img, float* __restrict__ ff) {
  int i = blockIdx.x * 256 + threadIdx.x;
  if (i >= B_ * 3 * HI_) return;
  int b = i / (3 * HI_), j = i % (3 * HI_);
  float vv;
  if (j < HI_) vv = ent[b * HI_ + j];
  else if (j < 2 * HI_) vv = ao[b * HI_ + j - HI_];
  else vv = img[b * HI_ + j - 2 * HI_];
  ff[i] = vv;
}

// ---------- first LSTM step (h=c=0): gates0 -> c0, HB[0] ----------
__global__ void lstm0(const float* __restrict__ g0, float* __restrict__ c0,
                      short* __restrict__ HB) {
  int i = blockIdx.x * 256 + threadIdx.x;
  if (i >= B_ * G_) return;
  int b = i >> 10, u = i & 1023;
  const float* gr = g0 + (long)b * 4096;
  float ig = gr[u], gg = gr[2048 + u], og = gr[3072 + u];
  float c = sigf(ig) * tanhf(gg);        // sig(f)*c_prev term is 0
  float h = sigf(og) * tanhf(c);
  c0[i] = c;
  HB[i] = to_bf16(h);                    // row (t=0)*32+b, col u  == b*1024+u
}

// ---------- embedding gather -> Xemb bf16 [4096][512] (row m=t*32+b, t=127 rows zero-pad) ----------
__global__ void gatherk(const float* __restrict__ emb, const int* __restrict__ sent,
                        short* __restrict__ Xemb) {
  int i = blockIdx.x * 256 + threadIdx.x;
  if (i >= 4096 * 512) return;
  int mrow = i >> 9, e = i & 511;
  int t = mrow >> 5, b = mrow & 31;
  float vv = 0.f;
  if (t < TSTEPS) { int w = sent[b * S_ + t]; vv = emb[(long)w * E_ + e]; }
  Xemb[i] = to_bf16(vv);
}

// ---------- 128x128 MFMA bf16 GEMM, C = A·B^T + bias (m97 structure) ----------
// mode 0: plain store C[m*N+n]  (Xg)
// mode 1: logits store with row remap (m>=32 -> out[b][t][v]), b=m&31, t=m/32-1
__global__ __launch_bounds__(256) void gemm_bt(const short* __restrict__ A,
                                               const short* __restrict__ Bm,
                                               const float* __restrict__ bias,
                                               float* __restrict__ C,
                                               int M, int N, int K, int mode) {
  __shared__ short As[128 * 32];
  __shared__ short Bs[128 * 32];
  const int tid = threadIdx.x;
  const int lane = tid & 63, wave = tid >> 6;
  const int n0 = blockIdx.x * 128, m0 = blockIdx.y * 128;
  const int l15 = lane & 15, quad = lane >> 4;
  const int mhalf = wave & 1, nhalf = wave >> 1;
  const int srow = lane >> 2;
  const int sseg = (lane & 3) * 8;
  v4f acc[4][4];
#pragma unroll
  for (int i = 0; i < 4; i++)
#pragma unroll
    for (int j = 0; j < 4; j++) acc[i][j] = (v4f){0.f, 0.f, 0.f, 0.f};
  const int kiters = K >> 5;
  for (int kt = 0; kt < kiters; ++kt) {
    const int k0 = kt * 32;
#pragma unroll
    for (int c = 0; c < 2; ++c) {
      const int chunk = wave * 2 + c;            // 0..7
      const int row = chunk * 16 + srow;
      load_lds16(A + (long)(m0 + row) * K + k0 + sseg, &As[chunk * 512]);
      load_lds16(Bm + (long)(n0 + row) * K + k0 + sseg, &Bs[chunk * 512]);
    }
    __syncthreads();
    v8s af[4], wf[4];
#pragma unroll
    for (int i = 0; i < 4; i++) af[i] = *(const v8s*)&As[(mhalf * 64 + i * 16 + l15) * 32 + quad * 8];
#pragma unroll
    for (int j = 0; j < 4; j++) wf[j] = *(const v8s*)&Bs[(nhalf * 64 + j * 16 + l15) * 32 + quad * 8];
#pragma unroll
    for (int i = 0; i < 4; i++)
#pragma unroll
      for (int j = 0; j < 4; j++)
        acc[i][j] = __builtin_amdgcn_mfma_f32_16x16x32_bf16(af[i], wf[j], acc[i][j], 0, 0, 0);
    __syncthreads();
  }
  // epilogue: D mapping col=lane&15 (=n), row=quad*4+reg (=m)
#pragma unroll
  for (int i = 0; i < 4; i++) {
    const int mb = m0 + mhalf * 64 + i * 16 + quad * 4;
#pragma unroll
    for (int j = 0; j < 4; j++) {
      const int nc = n0 + nhalf * 64 + j * 16 + l15;
      const float bv = bias[nc];
#pragma unroll
      for (int r = 0; r < 4; r++) {
        const int m = mb + r;
        float vv = acc[i][j][r] + bv;
        if (mode == 0) {
          C[(long)m * N + nc] = vv;
        } else if (m >= 32) {
          const int b = m & 31, t = (m >> 5) - 1;
          C[(long)b * LOGN + (long)t * V_ + nc] = vv;
        }
      }
    }
  }
}

// ---------- persistent LSTM scan: 127 steps, 128 blocks, W_hh slice resident in LDS ----------
// Barrier redesign (this round): no __threadfence (no buffer_wbl2 / buffer_inv L2 sweeps).
//  - h stores are device-scope WRITE-THROUGH (sc1) dword stores -> land at coherence point (L3);
//    L2 never holds dirty scan data, so no writeback fence is needed.
//  - release ordering hand-rolled: s_waitcnt vmcnt(0) + __syncthreads, then RELAXED agent store
//    of a per-block flag (distributed flag array: no RMW contention, no acquire-inv per poll).
//  - readers poll flags with RELAXED agent loads (sc1, bypass L1/L2). No reader invalidate:
//    within a launch each HB slot's lines are first cached only AFTER their final value is in
//    L3 (slot t written once at step t-1, read once at step t); launch-boundary acquire handles
//    cross-replay staleness.
//  - Xg for step t+1 prefetched into registers during the barrier wait.
__global__ __launch_bounds__(256) void lstm_scan(const float* __restrict__ Xg,
                                                 const short* __restrict__ Whh_b,
                                                 const float* __restrict__ c0,
                                                 short* __restrict__ HB,
                                                 unsigned* __restrict__ flags) {
  __shared__ short Wl[32 * 1032];   // 32 gate rows x 1024 (+8 pad) bf16
  __shared__ short Hl[32 * 1032];   // 32 batches  x 1024 (+8 pad) bf16
  __shared__ float gl[32 * 33];     // gates roundtrip [gate-row][batch]
  __shared__ float cl[256];         // c state [u][b], u=tid>>5 b=tid&31
  const int tid = threadIdx.x, nb = blockIdx.x;
  const int lane = tid & 63, wave = tid >> 6;
  const int l15 = lane & 15, quad = lane >> 4;
  const int mt = wave & 1, nt = wave >> 1;

  // stage W slice: lrow = u*4+g  <->  global gate row g*1024 + nb*8 + u
  for (int cid = tid; cid < 4096; cid += 256) {
    int lrow = cid >> 7;
    int koff = (cid & 127) * 8;
    int u = lrow >> 2, g = lrow & 3;
    const short* src = Whh_b + (long)(g * 1024 + nb * 8 + u) * 1024 + koff;
    *(v8s*)&Wl[lrow * 1032 + koff] = *(const v8s*)src;
  }
  const int eu = tid >> 5, eb = tid & 31, gu = nb * 8 + eu;
  cl[tid] = c0[eb * 1024 + gu];
  __syncthreads();

  // Xg prefetch for tt=0 (Xg row = tt*32+eb, cols gu + g*1024)
  float x0, x1, x2, x3;
  {
    const float* xr = Xg + (long)eb * 4096 + gu;
    x0 = xr[0]; x1 = xr[1024]; x2 = xr[2048]; x3 = xr[3072];
  }

  for (int tt = 0; tt < TSTEPS; ++tt) {
    // stage h_t slice (rows tt*32 .. +32) into LDS, coalesced
    {
      const short* hsrc = HB + (long)tt * 32 * 1024;
#pragma unroll
      for (int it = 0; it < 16; ++it) {
        int cid = it * 256 + tid;
        int row = cid >> 7;
        int koff = (cid & 127) * 8;
        *(v8s*)&Hl[row * 1032 + koff] = *(const v8s*)(hsrc + cid * 8);
      }
    }
    __syncthreads();
    // gates GEMM: wave (mt,nt): batches mt*16+l15, gate rows nt*16+l15
    // 2 accumulator chains to halve the dependent-MFMA serial latency
    v4f acc0 = (v4f){0.f, 0.f, 0.f, 0.f};
    v4f acc1 = (v4f){0.f, 0.f, 0.f, 0.f};
    {
      const short* aP = &Hl[(mt * 16 + l15) * 1032 + quad * 8];
      const short* wP = &Wl[(nt * 16 + l15) * 1032 + quad * 8];
#pragma unroll
      for (int kk = 0; kk < 32; kk += 2) {
        v8s a0 = *(const v8s*)(aP + kk * 32);
        v8s w0 = *(const v8s*)(wP + kk * 32);
        v8s a1 = *(const v8s*)(aP + (kk + 1) * 32);
        v8s w1 = *(const v8s*)(wP + (kk + 1) * 32);
        acc0 = __builtin_amdgcn_mfma_f32_16x16x32_bf16(a0, w0, acc0, 0, 0, 0);
        acc1 = __builtin_amdgcn_mfma_f32_16x16x32_bf16(a1, w1, acc1, 0, 0, 0);
      }
    }
#pragma unroll
    for (int r = 0; r < 4; ++r)
      gl[(nt * 16 + l15) * 33 + mt * 16 + quad * 4 + r] = acc0[r] + acc1[r];
    __syncthreads();
    // elementwise LSTM update: one (u,b) per thread; Xg addends were prefetched
    float ig = gl[(eu * 4 + 0) * 33 + eb] + x0;
    float fg = gl[(eu * 4 + 1) * 33 + eb] + x1;
    float gg = gl[(eu * 4 + 2) * 33 + eb] + x2;
    float og = gl[(eu * 4 + 3) * 33 + eb] + x3;
    float c = sigf(fg) * cl[tid] + sigf(ig) * tanhf(gg);
    float h = sigf(og) * tanhf(c);
    cl[tid] = c;
    // pack bf16 pair (cols gu, gu^1 across lane^32) -> device-scope write-through dword store
    unsigned hb = (unsigned)(unsigned short)to_bf16(h);
    unsigned ob = (unsigned)__shfl((int)hb, lane ^ 32, 64);
    if ((lane & 32) == 0) {
      unsigned packed = hb | (ob << 16);
      unsigned* dst = (unsigned*)HB + ((long)(tt + 1) * 32 + eb) * 512 + nb * 4 + wave;
      __hip_atomic_store(dst, packed, __ATOMIC_RELAXED, __HIP_MEMORY_SCOPE_AGENT);
    }
    // hand-rolled release: own stores acked at coherence point, then block-wide join
    asm volatile("s_waitcnt vmcnt(0)" ::: "memory");
    __syncthreads();
    if (tt < TSTEPS - 1) {
      if (tid == 0)
        __hip_atomic_store(flags + nb, (unsigned)(tt + 1), __ATOMIC_RELAXED, __HIP_MEMORY_SCOPE_AGENT);
      // prefetch next step's Xg while waiting on the barrier
      {
        const float* xn = Xg + ((long)(tt + 1) * 32 + eb) * 4096 + gu;
        x0 = xn[0]; x1 = xn[1024]; x2 = xn[2048]; x3 = xn[3072];
      }
      if (tid < 64) {
        const unsigned long long* fp = (const unsigned long long*)flags + tid;  // 2 flags each
        const unsigned tgt = (unsigned)(tt + 1);
        for (;;) {
          unsigned long long v = __hip_atomic_load(fp, __ATOMIC_RELAXED, __HIP_MEMORY_SCOPE_AGENT);
          if ((unsigned)v >= tgt && (unsigned)(v >> 32) >= tgt) break;
          __builtin_amdgcn_s_sleep(2);
        }
      }
      __syncthreads();
    }
  }
}

// ---------- launch ----------
extern "C" void kernel_launch(void* const* d_in, const int* in_sizes, int n_in,
                              void* d_out, int out_size, void* d_ws, size_t ws_size,
                              hipStream_t stream) {
  const float* ent  = (const float*)d_in[0];
  const float* nei  = (const float*)d_in[1];
  const int*   nnum = (const int*)d_in[2];
  const float* img  = (const float*)d_in[3];
  const int*   sent = (const int*)d_in[4];
  const int*   slen = (const int*)d_in[5];
  const float* emb  = (const float*)d_in[6];
  const float* Wih  = (const float*)d_in[7];
  const float* Whh  = (const float*)d_in[8];
  const float* bih  = (const float*)d_in[9];
  const float* bhh  = (const float*)d_in[10];
  const float* Wimg = (const float*)d_in[11];
  const float* bimg = (const float*)d_in[12];
  const float* Wout = (const float*)d_in[13];
  const float* bout = (const float*)d_in[14];
  const float* Wq = (const float*)d_in[15]; const float* bq = (const float*)d_in[16];
  const float* Wk = (const float*)d_in[17]; const float* bk = (const float*)d_in[18];
  const float* Wv = (const float*)d_in[19]; const float* bv = (const float*)d_in[20];
  const float* Wo = (const float*)d_in[21]; const float* bo = (const float*)d_in[22];
  float* out = (float*)d_out;

  char* ws = (char*)d_ws;
  short* Wout_b = (short*)(ws + 0L);                    // 65,536,000
  short* Whh_b  = (short*)(ws + 65536000L);             //  8,388,608
  short* Wih_b  = (short*)(ws + 73924608L);             //  4,194,304
  float* bsum   = (float*)(ws + 78118912L);             //     16,384
  short* Xemb   = (short*)(ws + 78135296L);             //  4,194,304
  short* HB     = (short*)(ws + 82329600L);             //  8,388,608 (128 t-slots x 32 x 1024 bf16)
  float* qbuf   = (float*)(ws + 90718208L);
  float* kbuf   = (float*)(ws + 90783744L);
  float* vbuf   = (float*)(ws + 91832320L);
  float* ctxb   = (float*)(ws + 92880896L);
  float* aob    = (float*)(ws + 92946432L);
  float* ffb    = (float*)(ws + 93011968L);
  float* ieb    = (float*)(ws + 93208576L);
  float* g0b    = (float*)(ws + 93274112L);
  float* c0b    = (float*)(ws + 93798400L);
  unsigned* flags = (unsigned*)(ws + 93929472L);        // 128 x u32 barrier flags
  // Xg (4096x4096 fp32, 67MB) parked in the logits region of d_out; fully consumed
  // by lstm_scan before the logits GEMM overwrites the region.
  float* Xg = out;
  float* outTail = out + (long)B_ * TSTEPS * V_;        // 130,048,000

  // 1) convert weights to bf16, bias sum, output passthrough, flags=0
  prep_kernel<<<16384, 256, 0, stream>>>(Wih, Whh, Wout, bih, bhh, sent, slen,
                                         Wih_b, Whh_b, Wout_b, bsum, outTail, flags);
  // 2) q/k/v projections
  dotk<<<64, 256, 0, stream>>>(ent, Wq, bq, qbuf, 32, 512, 512, 0);
  dotk<<<1024, 256, 0, stream>>>(nei, Wk, bk, kbuf, 512, 512, 512, 0);
  dotk<<<1024, 256, 0, stream>>>(nei, Wv, bv, vbuf, 512, 512, 512, 0);
  // 3) attention softmax + weighted V
  attnk<<<256, 64, 0, stream>>>(qbuf, kbuf, vbuf, nnum, ctxb);
  // 4) output projection of attention
  dotk<<<64, 256, 0, stream>>>(ctxb, Wo, bo, aob, 32, 512, 512, 0);
  // 5) concat + img embed (tanh)
  concatk<<<192, 256, 0, stream>>>(ent, aob, img, ffb);
  dotk<<<64, 256, 0, stream>>>(ffb, Wimg, bimg, ieb, 32, 512, 1536, 1);
  // 6) first LSTM step (h=c=0): gates then elementwise
  dotk<<<512, 256, 0, stream>>>(ieb, Wih, bsum, g0b, 32, 4096, 512, 0);
  lstm0<<<128, 256, 0, stream>>>(g0b, c0b, HB);
  // 7) embedding gather + Xg = Xemb @ W_ih^T + (b_ih+b_hh)  [one big MFMA GEMM]
  gatherk<<<8192, 256, 0, stream>>>(emb, sent, Xemb);
  gemm_bt<<<dim3(32, 32), 256, 0, stream>>>(Xemb, Wih_b, bsum, Xg, 4096, 4096, 512, 0);
  // 8) persistent recurrent scan (127 steps, distributed-flag device barrier)
  lstm_scan<<<SCAN_BLOCKS, 256, 0, stream>>>(Xg, Whh_b, c0b, HB, flags);
  // 9) all 127 logit projections as one GEMM: HB[4096][1024] @ W_out^T -> out[b][t][v]
  gemm_bt<<<dim3(250, 32), 256, 0, stream>>>(HB, Wout_b, bout, out, 4096, 32000, 1024, 1);
}